// Round 1
// baseline (264.363 us; speedup 1.0000x reference)
//
#include <hip/hip_runtime.h>
#include <hip/hip_bf16.h>
#include <math.h>

// KAN layer == GEMM: C[b,j] = sum_r A[b,r] * W[r,j],  A[b, i*5+k] = x[b,i]^k
// B=4096, D=1024, K=5, U=1024  ->  M=4096, Kdim=5120, N=1024, then bias + exact GELU.

#define B_DIM 4096
#define D_DIM 1024
#define KBASIS 5
#define U_DIM 1024
#define KT (D_DIM * KBASIS)   // 5120

typedef unsigned short ushort_t;
typedef __attribute__((ext_vector_type(8))) short bf16x8;   // 8 bf16 = 4 VGPRs (MFMA A/B frag)
typedef __attribute__((ext_vector_type(4))) float f32x4;    // MFMA C/D frag

// float -> bf16 round-to-nearest-even
__device__ __forceinline__ ushort_t f2bf(float f) {
  union { float f; unsigned int u; } v;
  v.f = f;
  unsigned int r = v.u + 0x7FFFu + ((v.u >> 16) & 1u);
  return (ushort_t)(r >> 16);
}

// async global->LDS DMA, 16B per lane; LDS dest = wave-uniform base + lane*16
__device__ __forceinline__ void load_lds16(const ushort_t* g, ushort_t* l) {
  __builtin_amdgcn_global_load_lds(
      (const __attribute__((address_space(1))) ushort_t*)g,
      (__attribute__((address_space(3))) ushort_t*)l, 16, 0, 0);
}

__device__ __forceinline__ float gelu_exact(float v) {
  return 0.5f * v * (1.0f + erff(v * 0.70710678118654752f));
}

// ---------------- prep 1: basis expansion x -> A (bf16) ----------------
// thread t handles 8 consecutive i for one row b: writes 40 bf16 = 80 B (5x uint4)
__global__ void basis_kernel(const float* __restrict__ x, ushort_t* __restrict__ A) {
  int t = blockIdx.x * blockDim.x + threadIdx.x;   // 4096*128 threads
  int b = t >> 7;
  int g = t & 127;
  const float4* xp = (const float4*)(x + (size_t)b * D_DIM + g * 8);
  float4 x0 = xp[0];
  float4 x1 = xp[1];
  float xs[8] = {x0.x, x0.y, x0.z, x0.w, x1.x, x1.y, x1.z, x1.w};
  ushort_t out[40];
#pragma unroll
  for (int ii = 0; ii < 8; ++ii) {
    float v = xs[ii];
    float p = 1.0f;
#pragma unroll
    for (int k = 0; k < KBASIS; ++k) {
      out[ii * KBASIS + k] = f2bf(p);   // x^0=1 exactly
      p *= v;
    }
  }
  uint4* dst = (uint4*)(A + (size_t)b * KT + g * 40);
  const uint4* src = (const uint4*)out;
#pragma unroll
  for (int c = 0; c < 5; ++c) dst[c] = src[c];
}

// ---------------- prep 2: W (5120,1024) fp32 -> WT (1024,5120) bf16 ----------------
__global__ void wt_kernel(const float* __restrict__ W, ushort_t* __restrict__ WT) {
  __shared__ ushort_t tile[32][33];   // +1 pad: no bank conflicts
  int r0 = blockIdx.x * 32;           // along KT
  int j0 = blockIdx.y * 32;           // along U
  int tx = threadIdx.x;               // 0..31
  int ty = threadIdx.y;               // 0..7
#pragma unroll
  for (int s = 0; s < 4; ++s) {
    int r = r0 + ty + s * 8;
    tile[ty + s * 8][tx] = f2bf(W[(size_t)r * U_DIM + j0 + tx]);  // coalesced read
  }
  __syncthreads();
#pragma unroll
  for (int s = 0; s < 4; ++s) {
    int j = j0 + ty + s * 8;
    WT[(size_t)j * KT + r0 + tx] = tile[tx][ty + s * 8];          // coalesced write
  }
}

// ---------------- main GEMM: 128x128 tile, BK=32, 4 waves, 16x16x32 bf16 MFMA ----------------
// LDS layout = fragment order: chunk c (16B) holds X[s*16 + (l&15)][(l>>4)*8 .. +8], s=c>>6, l=c&63.
// ds_read of a fragment is then 64 lanes * contiguous 16B -> conflict-free b128.
__global__ __launch_bounds__(256) void gemm_kernel(
    const ushort_t* __restrict__ A, const ushort_t* __restrict__ WT,
    const float* __restrict__ bias, float* __restrict__ C) {
  __shared__ ushort_t lA[128 * 32];   // 8 KB
  __shared__ ushort_t lB[128 * 32];   // 8 KB

  const int tid  = threadIdx.x;
  const int wave = tid >> 6;          // 0..3
  const int lane = tid & 63;
  const int wm   = wave >> 1;         // 2x2 wave grid, each wave 64x64
  const int wn   = wave & 1;
  const int tileM = blockIdx.y * 128;
  const int tileN = blockIdx.x * 128;

  const int lrow = lane & 15;
  const int lk8  = lane >> 4;         // 0..3 (which 8-wide k chunk)

  // per-thread global staging pointers (advance by BK=32 each iter)
  const ushort_t* ga0 = A  + (size_t)(tileM + wave * 16 + lrow) * KT + lk8 * 8;
  const ushort_t* ga1 = A  + (size_t)(tileM + (wave + 4) * 16 + lrow) * KT + lk8 * 8;
  const ushort_t* gb0 = WT + (size_t)(tileN + wave * 16 + lrow) * KT + lk8 * 8;
  const ushort_t* gb1 = WT + (size_t)(tileN + (wave + 4) * 16 + lrow) * KT + lk8 * 8;

  f32x4 acc[4][4];
  const f32x4 zero = {0.0f, 0.0f, 0.0f, 0.0f};
#pragma unroll
  for (int mf = 0; mf < 4; ++mf)
#pragma unroll
    for (int nf = 0; nf < 4; ++nf) acc[mf][nf] = zero;

  for (int kt = 0; kt < KT; kt += 32) {
    // stage tile kt (4 x 16B DMA per thread)
    load_lds16(ga0 + kt, &lA[(wave * 64 + lane) * 8]);
    load_lds16(ga1 + kt, &lA[((wave + 4) * 64 + lane) * 8]);
    load_lds16(gb0 + kt, &lB[(wave * 64 + lane) * 8]);
    load_lds16(gb1 + kt, &lB[((wave + 4) * 64 + lane) * 8]);
    __syncthreads();   // compiler drains vmcnt(0) before s_barrier

    bf16x8 af[4], bfr[4];
#pragma unroll
    for (int f = 0; f < 4; ++f) {
      af[f]  = *(const bf16x8*)&lA[((wm * 4 + f) * 64 + lane) * 8];
      bfr[f] = *(const bf16x8*)&lB[((wn * 4 + f) * 64 + lane) * 8];
    }
#pragma unroll
    for (int mf = 0; mf < 4; ++mf)
#pragma unroll
      for (int nf = 0; nf < 4; ++nf)
        acc[mf][nf] = __builtin_amdgcn_mfma_f32_16x16x32_bf16(af[mf], bfr[nf], acc[mf][nf], 0, 0, 0);
    __syncthreads();   // protect LDS before next overwrite
  }

  // epilogue: C/D map (m89): col = lane&15, row = (lane>>4)*4 + reg
  const int crow0 = tileM + wm * 64 + (lane >> 4) * 4;
  const int ccol0 = tileN + wn * 64 + (lane & 15);
#pragma unroll
  for (int nf = 0; nf < 4; ++nf) {
    const int col = ccol0 + nf * 16;
    const float bv = bias[col];
#pragma unroll
    for (int mf = 0; mf < 4; ++mf) {
#pragma unroll
      for (int r = 0; r < 4; ++r) {
        const int row = crow0 + mf * 16 + r;
        float v = acc[mf][nf][r] + bv;
        C[(size_t)row * U_DIM + col] = gelu_exact(v);
      }
    }
  }
}

// ---------------- fallback (only if ws too small): fp32, no workspace ----------------
__global__ void fallback_kernel(const float* __restrict__ x, const float* __restrict__ W,
                                const float* __restrict__ bias, float* __restrict__ out) {
  int j  = blockIdx.x * 256 + threadIdx.x;   // grid.x = U/256
  int b0 = blockIdx.y * 16;                  // grid.y = B/16
  float acc[16];
#pragma unroll
  for (int t = 0; t < 16; ++t) acc[t] = 0.0f;
  for (int i = 0; i < D_DIM; ++i) {
    const float* wr = W + (size_t)i * KBASIS * U_DIM + j;
    float w0 = wr[0 * U_DIM], w1 = wr[1 * U_DIM], w2 = wr[2 * U_DIM];
    float w3 = wr[3 * U_DIM], w4 = wr[4 * U_DIM];
#pragma unroll
    for (int t = 0; t < 16; ++t) {
      float xv = x[(size_t)(b0 + t) * D_DIM + i];
      float x2 = xv * xv;
      acc[t] += w0 + xv * w1 + x2 * w2 + x2 * xv * w3 + x2 * x2 * w4;
    }
  }
  float bv = bias[j];
#pragma unroll
  for (int t = 0; t < 16; ++t)
    out[(size_t)(b0 + t) * U_DIM + j] = gelu_exact(acc[t] + bv);
}

extern "C" void kernel_launch(void* const* d_in, const int* in_sizes, int n_in,
                              void* d_out, int out_size, void* d_ws, size_t ws_size,
                              hipStream_t stream) {
  const float* x    = (const float*)d_in[0];   // (4096, 1024)
  const float* W    = (const float*)d_in[1];   // (1024, 5, 1024)
  const float* bias = (const float*)d_in[2];   // (1024,)
  float* out = (float*)d_out;                  // (4096, 1024) fp32

  const size_t needA = (size_t)B_DIM * KT * sizeof(ushort_t);   // 41.94 MB
  const size_t needW = (size_t)U_DIM * KT * sizeof(ushort_t);   // 10.49 MB

  if (ws_size >= needA + needW) {
    ushort_t* Abf = (ushort_t*)d_ws;
    ushort_t* WT  = (ushort_t*)((char*)d_ws + needA);
    basis_kernel<<<dim3((B_DIM * 128) / 256), 256, 0, stream>>>(x, Abf);
    wt_kernel<<<dim3(KT / 32, U_DIM / 32), dim3(32, 8), 0, stream>>>(W, WT);
    gemm_kernel<<<dim3(U_DIM / 128, B_DIM / 128), 256, 0, stream>>>(Abf, WT, bias, out);
  } else {
    fallback_kernel<<<dim3(U_DIM / 256, B_DIM / 16), 256, 0, stream>>>(x, W, bias, out);
  }
}

// Round 2
// 186.718 us; speedup vs baseline: 1.4158x; 1.4158x over previous
//
#include <hip/hip_runtime.h>
#include <hip/hip_bf16.h>
#include <math.h>

// KAN layer == GEMM: C[b,j] = sum_r A[b,r] * W[r,j],  A[b, i*5+k] = x[b,i]^k
// B=4096, D=1024, K=5, U=1024  ->  M=4096, Kdim=5120, N=1024, then bias + exact GELU.
//
// Round 2: operands pre-packed in MFMA-unit order (1 KB units = [16 rows x 32 k]
// in lane-fragment layout), so every global_load_lds is a dense coalesced 1 KB
// burst. GEMM K-loop is a double-buffered DMA pipeline with ONE barrier/iter:
// tile k+1's DMA is issued before compute on tile k, so the pre-barrier vmcnt
// drain waits on loads that already had a compute-phase in flight.

#define B_DIM 4096
#define D_DIM 1024
#define KBASIS 5
#define U_DIM 1024
#define KT (D_DIM * KBASIS)   // 5120
#define NKBLK (KT / 32)       // 160 k-blocks of 32

typedef unsigned short ushort_t;
typedef __attribute__((ext_vector_type(8))) short bf16x8;   // 8 bf16 (MFMA A/B frag)
typedef __attribute__((ext_vector_type(4))) float f32x4;    // MFMA C/D frag

// packed addr (in ushorts) of element (row, k):
//   ((row>>4)*NKBLK + (k>>5))*512 + (((k>>3)&3)*16 + (row&15))*8 + (k&7)

__device__ __forceinline__ ushort_t f2bf(float f) {
  union { float f; unsigned int u; } v;
  v.f = f;
  unsigned int r = v.u + 0x7FFFu + ((v.u >> 16) & 1u);
  return (ushort_t)(r >> 16);
}

__device__ __forceinline__ void load_lds16(const ushort_t* g, ushort_t* l) {
  __builtin_amdgcn_global_load_lds(
      (const __attribute__((address_space(1))) ushort_t*)g,
      (__attribute__((address_space(3))) ushort_t*)l, 16, 0, 0);
}

__device__ __forceinline__ float gelu_exact(float v) {
  return 0.5f * v * (1.0f + erff(v * 0.70710678118654752f));
}

// ---------------- prep 1: basis expansion x -> A_packed ----------------
// block: 16 m-rows x 640 k (=128 i-values, 20 k-blocks). LDS-staged so global
// writes are fully coalesced 16B/lane; reads are coalesced float4.
__global__ __launch_bounds__(256) void basis_pack_kernel(
    const float* __restrict__ x, ushort_t* __restrict__ Ap) {
  __shared__ ushort_t st[20 * 512];   // 20 KB
  const int bx = blockIdx.x;          // 0..7   : k-chunk (640 k, 128 i)
  const int by = blockIdx.y;          // 0..255 : m16 block
  const int t  = threadIdx.x;
  const int m  = t >> 4;              // 0..15
  const int ig = t & 15;              // 0..15, each 8 i's
  const int i_loc0 = ig * 8;

  const float4* xp = (const float4*)(x + (size_t)(by * 16 + m) * D_DIM + bx * 128 + i_loc0);
  float4 x0 = xp[0];
  float4 x1 = xp[1];
  float xs[8] = {x0.x, x0.y, x0.z, x0.w, x1.x, x1.y, x1.z, x1.w};
#pragma unroll
  for (int ii = 0; ii < 8; ++ii) {
    float v = xs[ii];
    float p = 1.0f;
    int k_rel = (i_loc0 + ii) * KBASIS;   // 0..635
#pragma unroll
    for (int kb = 0; kb < KBASIS; ++kb, ++k_rel) {
      int pos = (k_rel >> 5) * 512 + ((((k_rel >> 3) & 3) * 16 + m) << 3) + (k_rel & 7);
      st[pos] = f2bf(p);
      p *= v;
    }
  }
  __syncthreads();
  // coalesced copy: 10240 ushorts = 1280 x uint4, 256 threads x 5
  uint4* dst = (uint4*)(Ap + ((size_t)by * NKBLK + bx * 20) * 512);
  const uint4* src = (const uint4*)st;
#pragma unroll
  for (int s = 0; s < 5; ++s) dst[t + s * 256] = src[t + s * 256];
}

// ---------------- prep 2: W (5120,1024) fp32 -> B_packed (bf16) ----------------
// block: 32 j x 64 r  -> 4 packed units (2 n16-blocks x 2 k-blocks).
__global__ __launch_bounds__(256) void w_pack_kernel(
    const float* __restrict__ W, ushort_t* __restrict__ Bp) {
  __shared__ ushort_t tile[32][72];   // +8 pad, rows 16B-aligned (144 B)
  const int j0 = blockIdx.x * 32;     // 0..992
  const int r0 = blockIdx.y * 64;     // 0..5056
  const int t  = threadIdx.x;
  const int j  = t & 31;
  const int rr = t >> 5;              // 0..7
#pragma unroll
  for (int s = 0; s < 8; ++s) {
    int r = rr + s * 8;
    tile[j][r] = f2bf(W[(size_t)(r0 + r) * U_DIM + j0 + j]);   // coalesced 128B/half-wave
  }
  __syncthreads();
  const int u  = t >> 6;              // 0..3 : unit
  const int l  = t & 63;
  const int jb = u >> 1;              // n16-block within tile
  const int rb = u & 1;               // k-block within tile
  const int jloc = jb * 16 + (l & 15);
  const int k8   = l >> 4;
  uint4 val = *(const uint4*)&tile[jloc][rb * 32 + k8 * 8];
  size_t base = ((size_t)(blockIdx.x * 2 + jb) * NKBLK + blockIdx.y * 2 + rb) * 512;
  *(uint4*)(Bp + base + l * 8) = val;   // dense 16B/lane
}

// ---------------- main GEMM: 128x128, BK=32, dbuf DMA pipeline ----------------
__global__ __launch_bounds__(256) void gemm_kernel(
    const ushort_t* __restrict__ Ap, const ushort_t* __restrict__ Bp,
    const float* __restrict__ bias, float* __restrict__ C) {
  __shared__ ushort_t lds[2][16 * 512];   // 2 x 16 KB (units 0..7 = A, 8..15 = B)

  const int tid  = threadIdx.x;
  const int wave = tid >> 6;
  const int lane = tid & 63;
  const int wm   = wave >> 1;
  const int wn   = wave & 1;
  const int tileM = blockIdx.y * 128;
  const int tileN = blockIdx.x * 128;

  // per-wave packed unit bases (ushort offsets); advance by 512 per k-block
  const ushort_t* ga0 = Ap + ((size_t)((tileM >> 4) + wave)     * NKBLK) * 512 + lane * 8;
  const ushort_t* ga1 = Ap + ((size_t)((tileM >> 4) + wave + 4) * NKBLK) * 512 + lane * 8;
  const ushort_t* gb0 = Bp + ((size_t)((tileN >> 4) + wave)     * NKBLK) * 512 + lane * 8;
  const ushort_t* gb1 = Bp + ((size_t)((tileN >> 4) + wave + 4) * NKBLK) * 512 + lane * 8;

  f32x4 acc[4][4];
  const f32x4 zero = {0.0f, 0.0f, 0.0f, 0.0f};
#pragma unroll
  for (int mf = 0; mf < 4; ++mf)
#pragma unroll
    for (int nf = 0; nf < 4; ++nf) acc[mf][nf] = zero;

#define STAGE(bb, kb)                                                        \
  do {                                                                       \
    load_lds16(ga0 + (size_t)(kb) * 512, &lds[bb][(wave)      * 512 + lane * 8]); \
    load_lds16(ga1 + (size_t)(kb) * 512, &lds[bb][(wave + 4)  * 512 + lane * 8]); \
    load_lds16(gb0 + (size_t)(kb) * 512, &lds[bb][(wave + 8)  * 512 + lane * 8]); \
    load_lds16(gb1 + (size_t)(kb) * 512, &lds[bb][(wave + 12) * 512 + lane * 8]); \
  } while (0)

  STAGE(0, 0);
  __syncthreads();   // drain tile 0

  for (int kb = 0; kb < NKBLK; ++kb) {
    const int cur = kb & 1;
    if (kb + 1 < NKBLK) STAGE(cur ^ 1, kb + 1);   // issue next tile's DMA first

    bf16x8 af[4], bfr[4];
#pragma unroll
    for (int f = 0; f < 4; ++f) {
      af[f]  = *(const bf16x8*)&lds[cur][(wm * 4 + f)     * 512 + lane * 8];
      bfr[f] = *(const bf16x8*)&lds[cur][(8 + wn * 4 + f) * 512 + lane * 8];
    }
#pragma unroll
    for (int mf = 0; mf < 4; ++mf)
#pragma unroll
      for (int nf = 0; nf < 4; ++nf)
        acc[mf][nf] = __builtin_amdgcn_mfma_f32_16x16x32_bf16(af[mf], bfr[nf], acc[mf][nf], 0, 0, 0);

    __syncthreads();   // drains next-tile DMA (issued a compute-phase ago) + read/write sync
  }
#undef STAGE

  // epilogue: C/D map: col = lane&15, row = (lane>>4)*4 + reg
  const int crow0 = tileM + wm * 64 + (lane >> 4) * 4;
  const int ccol0 = tileN + wn * 64 + (lane & 15);
#pragma unroll
  for (int nf = 0; nf < 4; ++nf) {
    const int col = ccol0 + nf * 16;
    const float bv = bias[col];
#pragma unroll
    for (int mf = 0; mf < 4; ++mf) {
#pragma unroll
      for (int r = 0; r < 4; ++r) {
        const int row = crow0 + mf * 16 + r;
        float v = acc[mf][nf][r] + bv;
        C[(size_t)row * U_DIM + col] = gelu_exact(v);
      }
    }
  }
}

// ---------------- fallback (only if ws too small): fp32, no workspace ----------------
__global__ void fallback_kernel(const float* __restrict__ x, const float* __restrict__ W,
                                const float* __restrict__ bias, float* __restrict__ out) {
  int j  = blockIdx.x * 256 + threadIdx.x;
  int b0 = blockIdx.y * 16;
  float acc[16];
#pragma unroll
  for (int t = 0; t < 16; ++t) acc[t] = 0.0f;
  for (int i = 0; i < D_DIM; ++i) {
    const float* wr = W + (size_t)i * KBASIS * U_DIM + j;
    float w0 = wr[0 * U_DIM], w1 = wr[1 * U_DIM], w2 = wr[2 * U_DIM];
    float w3 = wr[3 * U_DIM], w4 = wr[4 * U_DIM];
#pragma unroll
    for (int t = 0; t < 16; ++t) {
      float xv = x[(size_t)(b0 + t) * D_DIM + i];
      float x2 = xv * xv;
      acc[t] += w0 + xv * w1 + x2 * w2 + x2 * xv * w3 + x2 * x2 * w4;
    }
  }
  float bv = bias[j];
#pragma unroll
  for (int t = 0; t < 16; ++t)
    out[(size_t)(b0 + t) * U_DIM + j] = gelu_exact(acc[t] + bv);
}

extern "C" void kernel_launch(void* const* d_in, const int* in_sizes, int n_in,
                              void* d_out, int out_size, void* d_ws, size_t ws_size,
                              hipStream_t stream) {
  const float* x    = (const float*)d_in[0];   // (4096, 1024)
  const float* W    = (const float*)d_in[1];   // (1024, 5, 1024) -> rows r=i*5+k along KT
  const float* bias = (const float*)d_in[2];   // (1024,)
  float* out = (float*)d_out;                  // (4096, 1024) fp32

  const size_t needA = (size_t)B_DIM * KT * sizeof(ushort_t);   // 41.94 MB
  const size_t needW = (size_t)U_DIM * KT * sizeof(ushort_t);   // 10.49 MB

  if (ws_size >= needA + needW) {
    ushort_t* Ap = (ushort_t*)d_ws;
    ushort_t* Bp = (ushort_t*)((char*)d_ws + needA);
    basis_pack_kernel<<<dim3(D_DIM / 128, B_DIM / 16), 256, 0, stream>>>(x, Ap);
    w_pack_kernel<<<dim3(U_DIM / 32, KT / 64), 256, 0, stream>>>(W, Bp);
    gemm_kernel<<<dim3(U_DIM / 128, B_DIM / 128), 256, 0, stream>>>(Ap, Bp, bias, out);
  } else {
    fallback_kernel<<<dim3(U_DIM / 256, B_DIM / 16), 256, 0, stream>>>(x, W, bias, out);
  }
}

// Round 3
// 143.012 us; speedup vs baseline: 1.8485x; 1.3056x over previous
//
#include <hip/hip_runtime.h>
#include <hip/hip_bf16.h>
#include <math.h>

// KAN layer: out = GELU( einsum('bik,ikj->bj', basis, W) + bias ),
//   basis[b,i,k] = x[b,i]^k, B=4096, D=1024, K=5, U=1024.
//
// Round 3: (1) k=0 plane is all-ones -> fold sum_i W[i,0,j] into bias;
// GEMM K drops 5120 -> 4096. A[b, i*4+e] = x^(e+1), Wp[j, i*4+e] = W[i,e+1,j].
// (2) tile 64x128 -> grid 512 = 2 blocks/CU so one block computes while the
// other drains its barrier. (3) BK=64 (2 k-units per barrier) to amortize drain.
// Operands pre-packed in MFMA-unit order (1 KB units: lane l holds row l&15,
// k-octet l>>4) so every global_load_lds is a dense coalesced 1 KB burst.

#define B_DIM 4096
#define D_DIM 1024
#define U_DIM 1024
#define KT2 4096            // GEMM K after dropping k=0 plane
#define NKB 128             // 32-wide k-blocks

typedef unsigned short ushort_t;
typedef __attribute__((ext_vector_type(8))) short bf16x8;   // MFMA A/B frag
typedef __attribute__((ext_vector_type(4))) float f32x4;    // MFMA C/D frag

__device__ __forceinline__ ushort_t f2bf(float f) {
  union { float f; unsigned int u; } v;
  v.f = f;
  unsigned int r = v.u + 0x7FFFu + ((v.u >> 16) & 1u);
  return (ushort_t)(r >> 16);
}

__device__ __forceinline__ void load_lds16(const ushort_t* g, ushort_t* l) {
  __builtin_amdgcn_global_load_lds(
      (const __attribute__((address_space(1))) ushort_t*)g,
      (__attribute__((address_space(3))) ushort_t*)l, 16, 0, 0);
}

__device__ __forceinline__ float gelu_exact(float v) {
  return 0.5f * v * (1.0f + erff(v * 0.70710678118654752f));
}

// packed addr (ushorts) of (row, k): ((row>>4)*NKB + (k>>5))*512
//                                     + (((k>>3)&3)*16 + (row&15))*8 + (k&7)

// ---------------- prep 1: x -> A_packed (powers 1..4), direct stores ----------------
// one thread = one 16B chunk = 2 i-values x 4 powers. Wave = one 1 KB unit.
__global__ __launch_bounds__(256) void basis_pack_kernel(
    const float* __restrict__ x, ushort_t* __restrict__ Ap) {
  const int t    = threadIdx.x;
  const int wave = t >> 6;
  const int lane = t & 63;
  const int kblk = blockIdx.x * 4 + wave;     // 0..127
  const int m16  = blockIdx.y;                // 0..255
  const int m    = lane & 15;
  const int ko   = lane >> 4;                 // k-octet 0..3
  const int row  = m16 * 16 + m;
  const int i0   = kblk * 8 + ko * 2;

  const float xa = x[(size_t)row * D_DIM + i0];
  const float xb = x[(size_t)row * D_DIM + i0 + 1];
  const float xa2 = xa * xa, xb2 = xb * xb;
  ushort_t o[8];
  o[0] = f2bf(xa);  o[1] = f2bf(xa2); o[2] = f2bf(xa2 * xa); o[3] = f2bf(xa2 * xa2);
  o[4] = f2bf(xb);  o[5] = f2bf(xb2); o[6] = f2bf(xb2 * xb); o[7] = f2bf(xb2 * xb2);
  *(uint4*)(Ap + ((size_t)m16 * NKB + kblk) * 512 + lane * 8) = *(const uint4*)o;
}

// ---------------- prep 2: W -> B_packed (planes 1..4), direct gather ----------------
__global__ __launch_bounds__(256) void w_pack_kernel(
    const float* __restrict__ W, ushort_t* __restrict__ Bp) {
  const int t    = threadIdx.x;
  const int wave = t >> 6;
  const int lane = t & 63;
  const int kblk = blockIdx.x * 4 + wave;     // 0..127
  const int n16  = blockIdx.y;                // 0..63
  const int jj   = lane & 15;
  const int ko   = lane >> 4;
  const int j    = n16 * 16 + jj;
  const int i0   = kblk * 8 + ko * 2;

  ushort_t o[8];
#pragma unroll
  for (int t2 = 0; t2 < 2; ++t2) {
    const int i = i0 + t2;
#pragma unroll
    for (int e = 0; e < 4; ++e) {
      const int r = i * 5 + e + 1;            // skip k=0 plane
      o[t2 * 4 + e] = f2bf(W[(size_t)r * U_DIM + j]);
    }
  }
  *(uint4*)(Bp + ((size_t)n16 * NKB + kblk) * 512 + lane * 8) = *(const uint4*)o;
}

// ---------------- prep 3: fold k=0 plane into bias ----------------
__global__ __launch_bounds__(256) void fold_part_kernel(
    const float* __restrict__ W, float* __restrict__ part) {
  const int j = blockIdx.x * 256 + threadIdx.x;   // grid.x = 4
  const int g = blockIdx.y;                        // 0..31
  float s = 0.0f;
#pragma unroll 8
  for (int ii = 0; ii < 32; ++ii) {
    const int i = g * 32 + ii;
    s += W[(size_t)(i * 5) * U_DIM + j];
  }
  part[(size_t)g * U_DIM + j] = s;
}

__global__ __launch_bounds__(256) void fold_final_kernel(
    const float* __restrict__ part, const float* __restrict__ bias,
    float* __restrict__ bias2) {
  const int j = blockIdx.x * 256 + threadIdx.x;   // grid.x = 4
  float s = bias[j];
#pragma unroll
  for (int g = 0; g < 32; ++g) s += part[(size_t)g * U_DIM + j];
  bias2[j] = s;
}

// ---------------- main GEMM: 64x128 tile, BK=64, dbuf DMA pipeline ----------------
// buffer layout: unit u = ku*12 + r (ku = k-unit 0/1); r 0..3 = A m16 r,
// r 4..11 = B n16 r-4. 24 KB per buffer, x2.
__global__ __launch_bounds__(256) void gemm_kernel(
    const ushort_t* __restrict__ Ap, const ushort_t* __restrict__ Bp,
    const float* __restrict__ bias2, float* __restrict__ C) {
  __shared__ ushort_t lds[2][24 * 512];   // 2 x 24 KB

  const int tid  = threadIdx.x;
  const int wave = tid >> 6;
  const int lane = tid & 63;
  const int wm   = wave >> 1;             // 0..1 : 32-row half
  const int wn   = wave & 1;              // 0..1 : 64-col half
  const int m16b = blockIdx.y * 4;        // tile M=64 -> 4 m16 blocks
  const int n16b = blockIdx.x * 8;        // tile N=128 -> 8 n16 blocks

  // staging assignment: s=0..5, unit u = s*4 + wave (dense 1 KB bursts)
  const ushort_t* gsrc[6];
  int ldst[6];
#pragma unroll
  for (int s = 0; s < 6; ++s) {
    const int u  = s * 4 + wave;
    const int ku = (u >= 12) ? 1 : 0;
    const int r  = u - ku * 12;
    const ushort_t* base = (r < 4)
        ? Ap + ((size_t)(m16b + r) * NKB) * 512
        : Bp + ((size_t)(n16b + (r - 4)) * NKB) * 512;
    gsrc[s] = base + (size_t)ku * 512 + lane * 8;
    ldst[s] = u * 512 + lane * 8;
  }

  f32x4 acc[2][4];
  const f32x4 zero = {0.0f, 0.0f, 0.0f, 0.0f};
#pragma unroll
  for (int mf = 0; mf < 2; ++mf)
#pragma unroll
    for (int nf = 0; nf < 4; ++nf) acc[mf][nf] = zero;

#define STAGE(bb, it)                                                   \
  do {                                                                  \
    _Pragma("unroll")                                                   \
    for (int s = 0; s < 6; ++s)                                         \
      load_lds16(gsrc[s] + (size_t)(it) * 1024, &lds[bb][ldst[s]]);     \
  } while (0)

  STAGE(0, 0);
  __syncthreads();

  for (int it = 0; it < 64; ++it) {
    const int cur = it & 1;
    if (it + 1 < 64) STAGE(cur ^ 1, it + 1);   // DMA for next iter, in flight
                                               // across this iter's compute
#pragma unroll
    for (int ku = 0; ku < 2; ++ku) {
      bf16x8 a[2], b[4];
#pragma unroll
      for (int mf = 0; mf < 2; ++mf)
        a[mf] = *(const bf16x8*)&lds[cur][(ku * 12 + wm * 2 + mf) * 512 + lane * 8];
#pragma unroll
      for (int nf = 0; nf < 4; ++nf)
        b[nf] = *(const bf16x8*)&lds[cur][(ku * 12 + 4 + wn * 4 + nf) * 512 + lane * 8];
#pragma unroll
      for (int mf = 0; mf < 2; ++mf)
#pragma unroll
        for (int nf = 0; nf < 4; ++nf)
          acc[mf][nf] = __builtin_amdgcn_mfma_f32_16x16x32_bf16(a[mf], b[nf], acc[mf][nf], 0, 0, 0);
    }
    __syncthreads();   // releases cur for overwrite + drains next-iter DMA
  }
#undef STAGE

  // epilogue: C/D map: col = lane&15, row = (lane>>4)*4 + reg
  const int crow0 = m16b * 16 + wm * 32 + (lane >> 4) * 4;
  const int ccol0 = n16b * 16 + wn * 64 + (lane & 15);
#pragma unroll
  for (int nf = 0; nf < 4; ++nf) {
    const int col = ccol0 + nf * 16;
    const float bv = bias2[col];
#pragma unroll
    for (int mf = 0; mf < 2; ++mf) {
#pragma unroll
      for (int r = 0; r < 4; ++r) {
        const int row = crow0 + mf * 16 + r;
        C[(size_t)row * U_DIM + col] = gelu_exact(acc[mf][nf][r] + bv);
      }
    }
  }
}

// ---------------- fallback (ws too small): fp32, no workspace ----------------
__global__ void fallback_kernel(const float* __restrict__ x, const float* __restrict__ W,
                                const float* __restrict__ bias, float* __restrict__ out) {
  int j  = blockIdx.x * 256 + threadIdx.x;
  int b0 = blockIdx.y * 16;
  float acc[16];
#pragma unroll
  for (int t = 0; t < 16; ++t) acc[t] = 0.0f;
  for (int i = 0; i < D_DIM; ++i) {
    const float* wr = W + (size_t)i * 5 * U_DIM + j;
    float w0 = wr[0 * U_DIM], w1 = wr[1 * U_DIM], w2 = wr[2 * U_DIM];
    float w3 = wr[3 * U_DIM], w4 = wr[4 * U_DIM];
#pragma unroll
    for (int t = 0; t < 16; ++t) {
      float xv = x[(size_t)(b0 + t) * D_DIM + i];
      float x2 = xv * xv;
      acc[t] += w0 + xv * w1 + x2 * w2 + x2 * xv * w3 + x2 * x2 * w4;
    }
  }
  float bv = bias[j];
#pragma unroll
  for (int t = 0; t < 16; ++t)
    out[(size_t)(b0 + t) * U_DIM + j] = gelu_exact(acc[t] + bv);
}

extern "C" void kernel_launch(void* const* d_in, const int* in_sizes, int n_in,
                              void* d_out, int out_size, void* d_ws, size_t ws_size,
                              hipStream_t stream) {
  const float* x    = (const float*)d_in[0];   // (4096, 1024)
  const float* W    = (const float*)d_in[1];   // (1024, 5, 1024), row r = i*5+k
  const float* bias = (const float*)d_in[2];   // (1024,)
  float* out = (float*)d_out;                  // (4096, 1024) fp32

  const size_t szA = (size_t)B_DIM * KT2 * sizeof(ushort_t);   // 33.55 MB
  const size_t szB = (size_t)U_DIM * KT2 * sizeof(ushort_t);   //  8.39 MB
  const size_t szP = (size_t)32 * U_DIM * sizeof(float);       //  128 KB
  const size_t szb = (size_t)U_DIM * sizeof(float);            //    4 KB

  if (ws_size >= szA + szB + szP + szb) {
    ushort_t* Ap   = (ushort_t*)d_ws;
    ushort_t* Bp   = (ushort_t*)((char*)d_ws + szA);
    float*    part = (float*)((char*)d_ws + szA + szB);
    float*    b2   = (float*)((char*)d_ws + szA + szB + szP);
    basis_pack_kernel<<<dim3(NKB / 4, B_DIM / 16), 256, 0, stream>>>(x, Ap);
    w_pack_kernel<<<dim3(NKB / 4, U_DIM / 16), 256, 0, stream>>>(W, Bp);
    fold_part_kernel<<<dim3(U_DIM / 256, 32), 256, 0, stream>>>(W, part);
    fold_final_kernel<<<dim3(U_DIM / 256), 256, 0, stream>>>(part, bias, b2);
    gemm_kernel<<<dim3(U_DIM / 128, B_DIM / 64), 256, 0, stream>>>(Ap, Bp, b2, out);
  } else {
    fallback_kernel<<<dim3(U_DIM / 256, B_DIM / 16), 256, 0, stream>>>(x, W, bias, out);
  }
}